// Round 6
// baseline (1695.007 us; speedup 1.0000x reference)
//
#include <hip/hip_runtime.h>

#define N_ROWS 65536
#define DIM    512
#define K_CENT 4096
#define TILE_M 128
#define TILE_N 256
#define BK     64
#define KSTEPS (DIM / BK)        // 8
#define NKT    (K_CENT / TILE_N) // 16
#define THREADS 512
#define MARGIN 22.0f
#define CAND_CAP 1536
#define COMPACT_TRIG 1024
#define SCALE1 0x7F7F7F7F        // e8m0 scale = 2^0 in every byte

typedef float  floatx4  __attribute__((ext_vector_type(4)));
typedef float  floatx16 __attribute__((ext_vector_type(16)));
typedef int    intx2    __attribute__((ext_vector_type(2)));
typedef int    intx4    __attribute__((ext_vector_type(4)));
typedef int    intx8    __attribute__((ext_vector_type(8)));

// order-preserving float<->uint map
__device__ __forceinline__ unsigned mapF(float f) {
  unsigned u = __float_as_uint(f);
  return (u & 0x80000000u) ? ~u : (u | 0x80000000u);
}
__device__ __forceinline__ float unmapF(unsigned m) {
  unsigned u = (m & 0x80000000u) ? (m ^ 0x80000000u) : ~m;
  return __uint_as_float(u);
}

__device__ __forceinline__ void gload_lds16(const void* g, void* l) {
  __builtin_amdgcn_global_load_lds(
      (const __attribute__((address_space(1))) void*)g,
      (__attribute__((address_space(3))) void*)l, 16, 0, 0);
}

// pack 4 floats -> 4 OCP e4m3 bytes (v_cvt_pk_fp8_f32; OCP format on gfx950)
__device__ __forceinline__ int pk4(float a, float b, float c, float d) {
  int r = __builtin_amdgcn_cvt_pk_fp8_f32(a, b, 0, false);
  r = __builtin_amdgcn_cvt_pk_fp8_f32(c, d, r, true);
  return r;
}

// fp32 -> fp8 for x and center; EXACT fp32 csq fused into the center branch
// (one 64-lane wave covers one 512-dim center row).
__global__ void prep_convert(const float* __restrict__ x, const float* __restrict__ c,
                             unsigned char* __restrict__ xq, unsigned char* __restrict__ cq,
                             float* __restrict__ csqg) {
  const size_t nx = (size_t)N_ROWS * DIM;
  size_t i = ((size_t)blockIdx.x * blockDim.x + threadIdx.x) * 8;
  if (i < nx) {
    floatx4 a = *(const floatx4*)(x + i);
    floatx4 b = *(const floatx4*)(x + i + 4);
    intx2 q = { pk4(a[0], a[1], a[2], a[3]), pk4(b[0], b[1], b[2], b[3]) };
    *(intx2*)(xq + i) = q;
  } else if (i < nx + (size_t)K_CENT * DIM) {
    size_t off = i - nx;
    floatx4 a = *(const floatx4*)(c + off);
    floatx4 b = *(const floatx4*)(c + off + 4);
    intx2 q = { pk4(a[0], a[1], a[2], a[3]), pk4(b[0], b[1], b[2], b[3]) };
    *(intx2*)(cq + off) = q;
    float s = a[0]*a[0]+a[1]*a[1]+a[2]*a[2]+a[3]*a[3]
            + b[0]*b[0]+b[1]*b[1]+b[2]*b[2]+b[3]*b[3];
#pragma unroll
    for (int o = 1; o < 64; o <<= 1) s += __shfl_xor(s, o, 64);
    if ((threadIdx.x & 63) == 0) csqg[off >> 9] = s;
  }
}

// MODE 0: no ws (fp32 loads, in-kernel fp8 cvt + ds_write, LDS csq)
// MODE 2: fp8 + exact-fp32 csq pre-computed in ws
//
// 512 threads = 8 waves (2 wave-rows x 4 wave-cols), block tile 128x256,
// wave tile 64x64 = 2x2 of mfma_scale_f32_32x32x64_f8f6f4 (unit scales),
// BK=64 -> KSTEPS=8 (half the barriers of the f16 version), grid 512
// (2 blocks/CU, 16 waves). Single pass: tighten per-row running min
// (shfl-reduced over 32 cols), barrier, collect vs runmin+MARGIN
// (prefix-threshold superset), fp64-exact refine of survivors.
// LDS tile layout: 16B slot s = rg*128 + r32*4 + (c ^ ((r32>>1)&3));
// glds-compatible (lane-contiguous slots, 4 lanes = one row's 64B) AND
// conflict-free for the 32-lane b128 fragment reads (hand-checked residues).
// Reg budget: 64 acc + 32 frag + addr ~= 125/wave -> 4 waves/SIMD via
// __launch_bounds__(512,4). NEVER (512,8): R4 spilled acc (8.9GB scratch).
template <int MODE>
__global__ __launch_bounds__(THREADS, 4)
void kmeans_argmin(const float* __restrict__ x, const float* __restrict__ cent,
                   const unsigned char* __restrict__ xq, const unsigned char* __restrict__ cq,
                   const float* __restrict__ csqg, int* __restrict__ out) {
  __shared__ unsigned char ldsA[TILE_M * BK];   // 8 KB  (512 slots)
  __shared__ unsigned char ldsB[TILE_N * BK];   // 16 KB (1024 slots)
  __shared__ float csq4[TILE_N][4];             // 4 KB (MODE 0 only)
  __shared__ unsigned sminU[TILE_M];
  __shared__ unsigned long long best[TILE_M];
  __shared__ unsigned candKey[CAND_CAP];        // 6 KB
  __shared__ float candS[CAND_CAP];             // 6 KB
  __shared__ int candCount;

  const int t = threadIdx.x;
  const int lane = t & 63;
  const int wave = t >> 6;   // 0..7
  const int wm = wave >> 2;  // 0..1 row-waves
  const int wn = wave & 3;   // 0..3 col-waves
  const int l31 = lane & 31;
  const int half = lane >> 5;           // 0..1
  const int rowBlock = blockIdx.x * TILE_M;

  if (t < TILE_M) { sminU[t] = 0xFFFFFFFFu; best[t] = ~0ull; }
  if (t == 0) candCount = 0;

  // staging slot decode: slot s -> row = (s>>7)*32 + ((s>>2)&31),
  // chunk c = (s&3) ^ ((((s>>2)&31)>>1)&3), byte offset c*16 within row's 64B
  const int sA = t;                 // A: 512 slots
  const int rA = ((sA >> 2) & 31);
  const int rowA = (sA >> 7) * 32 + rA;
  const int offA = (((sA & 3) ^ ((rA >> 1) & 3)) << 4);
  const int sB0 = t, sB1 = t + 512; // B: 1024 slots
  const int rB0 = ((sB0 >> 2) & 31);
  const int rowB0 = (sB0 >> 7) * 32 + rB0;
  const int offB0 = (((sB0 & 3) ^ ((rB0 >> 1) & 3)) << 4);
  const int rB1 = ((sB1 >> 2) & 31);
  const int rowB1 = (sB1 >> 7) * 32 + rB1;
  const int offB1 = (((sB1 & 3) ^ ((rB1 >> 1) & 3)) << 4);

  // fragment read slots (per lane, constant): row r=l31, chunks q,q^1
  const int qk = half * 2;                       // first (unswizzled) chunk
  const int fragSlotBase = 4 * l31 + (qk ^ ((l31 >> 1) & 3)); // + rg*128; pair = ^1

  for (int kt = 0; kt < NKT; ++kt) {
    const int ktBase = kt * TILE_N;
    if (MODE == 0) { ((float*)csq4)[t] = 0.f; ((float*)csq4)[t + 512] = 0.f; }
    floatx16 acc[2][2];
#pragma unroll
    for (int fm = 0; fm < 2; ++fm)
#pragma unroll
      for (int fn = 0; fn < 2; ++fn)
#pragma unroll
        for (int e = 0; e < 16; ++e) acc[fm][fn][e] = 0.f;

    for (int ks = 0; ks < KSTEPS; ++ks) {
      const int kd = ks * BK;
      if (MODE == 2) {
        gload_lds16(xq + (size_t)(rowBlock + rowA) * DIM + kd + offA,
                    ldsA + (size_t)wave * 1024);
        gload_lds16(cq + (size_t)(ktBase + rowB0) * DIM + kd + offB0,
                    ldsB + (size_t)wave * 1024);
        gload_lds16(cq + (size_t)(ktBase + rowB1) * DIM + kd + offB1,
                    ldsB + 8192 + (size_t)wave * 1024);
      } else {
        // fallback: fp32 loads, in-kernel cvt to fp8, ds_write; exact csq in LDS
        {
          const float* gA = x + (size_t)(rowBlock + rowA) * DIM + kd + offA;
          floatx4 f0 = *(const floatx4*)gA, f1 = *(const floatx4*)(gA + 4);
          floatx4 f2 = *(const floatx4*)(gA + 8), f3 = *(const floatx4*)(gA + 12);
          intx4 q = { pk4(f0[0],f0[1],f0[2],f0[3]), pk4(f1[0],f1[1],f1[2],f1[3]),
                      pk4(f2[0],f2[1],f2[2],f2[3]), pk4(f3[0],f3[1],f3[2],f3[3]) };
          *(intx4*)(ldsA + (size_t)sA * 16) = q;
        }
#pragma unroll
        for (int p = 0; p < 2; ++p) {
          int row = p ? rowB1 : rowB0;
          int off = p ? offB1 : offB0;
          int slot = p ? sB1 : sB0;
          const float* gB = cent + (size_t)(ktBase + row) * DIM + kd + off;
          floatx4 f0 = *(const floatx4*)gB, f1 = *(const floatx4*)(gB + 4);
          floatx4 f2 = *(const floatx4*)(gB + 8), f3 = *(const floatx4*)(gB + 12);
          intx4 q = { pk4(f0[0],f0[1],f0[2],f0[3]), pk4(f1[0],f1[1],f1[2],f1[3]),
                      pk4(f2[0],f2[1],f2[2],f2[3]), pk4(f3[0],f3[1],f3[2],f3[3]) };
          *(intx4*)(ldsB + (size_t)slot * 16) = q;
          float s = 0.f;
#pragma unroll
          for (int e = 0; e < 4; ++e)
            s += f0[e]*f0[e] + f1[e]*f1[e] + f2[e]*f2[e] + f3[e]*f3[e];
          csq4[row][slot & 3] += s;
        }
      }
      __syncthreads();

      intx8 aF[2], bF[2];
#pragma unroll
      for (int fm = 0; fm < 2; ++fm) {
        int s0 = (wm * 2 + fm) * 128 + fragSlotBase;
        intx4 lo = *(const intx4*)(ldsA + s0 * 16);
        intx4 hi = *(const intx4*)(ldsA + (s0 ^ 1) * 16);
        aF[fm] = (intx8){lo[0], lo[1], lo[2], lo[3], hi[0], hi[1], hi[2], hi[3]};
      }
#pragma unroll
      for (int fn = 0; fn < 2; ++fn) {
        int s0 = (wn * 2 + fn) * 128 + fragSlotBase;
        intx4 lo = *(const intx4*)(ldsB + s0 * 16);
        intx4 hi = *(const intx4*)(ldsB + (s0 ^ 1) * 16);
        bF[fn] = (intx8){lo[0], lo[1], lo[2], lo[3], hi[0], hi[1], hi[2], hi[3]};
      }
#pragma unroll
      for (int fm = 0; fm < 2; ++fm)
#pragma unroll
        for (int fn = 0; fn < 2; ++fn)
          acc[fm][fn] = __builtin_amdgcn_mfma_scale_f32_32x32x64_f8f6f4(
              aF[fm], bF[fn], acc[fm][fn], 0, 0, 0, SCALE1, 0, SCALE1);
      __syncthreads();
    }

    // ---- epilogue: s = ||c||^2_exact - 2*cross  (||x||^2 constant per row)
    // C/D 32x32 layout: col = lane&31, row = (reg&3)+8*(reg>>2)+4*(lane>>5)
    float cs[2];
#pragma unroll
    for (int fn = 0; fn < 2; ++fn) {
      int col = ktBase + wn * 64 + fn * 32 + l31;
      cs[fn] = (MODE == 2) ? csqg[col]
                           : (csq4[wn*64+fn*32+l31][0] + csq4[wn*64+fn*32+l31][1] +
                              csq4[wn*64+fn*32+l31][2] + csq4[wn*64+fn*32+l31][3]);
    }

    // tighten running min first: min over fn + shfl-reduce over the 32 cols
#pragma unroll
    for (int fm = 0; fm < 2; ++fm)
#pragma unroll
      for (int r = 0; r < 16; ++r) {
        float v = fminf(cs[0] - 2.f * acc[fm][0][r], cs[1] - 2.f * acc[fm][1][r]);
        v = fminf(v, __shfl_xor(v, 1, 64));
        v = fminf(v, __shfl_xor(v, 2, 64));
        v = fminf(v, __shfl_xor(v, 4, 64));
        v = fminf(v, __shfl_xor(v, 8, 64));
        v = fminf(v, __shfl_xor(v, 16, 64));
        if (l31 == 0) {
          int srow = wm * 64 + fm * 32 + (r & 3) + 8 * (r >> 2) + 4 * half;
          atomicMin(&sminU[srow], mapF(v));
        }
      }
    __syncthreads();

    // collect against the tightened (prefix, hence superset) threshold
#pragma unroll
    for (int fm = 0; fm < 2; ++fm)
#pragma unroll
      for (int r = 0; r < 16; ++r) {
        int srow = wm * 64 + fm * 32 + (r & 3) + 8 * (r >> 2) + 4 * half;
        float thr = unmapF(sminU[srow]) + MARGIN;
#pragma unroll
        for (int fn = 0; fn < 2; ++fn) {
          float s = cs[fn] - 2.f * acc[fm][fn][r];
          if (s <= thr) {
            int k = ktBase + wn * 64 + fn * 32 + l31;
            int idx = atomicAdd(&candCount, 1);
            if (idx < CAND_CAP) {
              candKey[idx] = ((unsigned)k << 7) | (unsigned)srow;
              candS[idx] = s;
            }
          }
        }
      }
    __syncthreads();

    // compaction backstop (rarely triggers)
    if (candCount > COMPACT_TRIG) {
      int cc = candCount; if (cc > CAND_CAP) cc = CAND_CAP;
      unsigned myK[4]; float myS[4]; int myN = 0;
      for (int i = t; i < cc; i += THREADS) {
        int rl = candKey[i] & 127;
        if (candS[i] <= unmapF(sminU[rl]) + MARGIN && myN < 4) {
          myK[myN] = candKey[i]; myS[myN] = candS[i]; ++myN;
        }
      }
      __syncthreads();
      if (t == 0) candCount = 0;
      __syncthreads();
      int base = atomicAdd(&candCount, myN);
      for (int j = 0; j < myN; ++j) { candKey[base + j] = myK[j]; candS[base + j] = myS[j]; }
      __syncthreads();
    }
  }

  // ---- fp64-exact refinement of surviving candidates (original fp32 inputs)
  int cnt = candCount; if (cnt > CAND_CAP) cnt = CAND_CAP;
  const int g = t >> 4;   // 32 groups of 16 lanes
  const int sl = t & 15;
  for (int ci = g; ci < cnt; ci += 32) {
    unsigned cd = candKey[ci];
    int rl = cd & 127;
    if (candS[ci] > unmapF(sminU[rl]) + MARGIN) continue;  // group-uniform branch
    int k = cd >> 7;
    const float* xr = x + (size_t)(rowBlock + rl) * DIM;
    const float* cr = cent + (size_t)k * DIM;
    double d = 0.0;
#pragma unroll
    for (int j = 0; j < DIM / 64; ++j) {
      floatx4 xv = *(const floatx4*)(xr + j * 64 + sl * 4);
      floatx4 cv = *(const floatx4*)(cr + j * 64 + sl * 4);
#pragma unroll
      for (int e = 0; e < 4; ++e) {
        double df = (double)xv[e] - (double)cv[e];
        d += df * df;
      }
    }
#pragma unroll
    for (int off = 1; off < 16; off <<= 1) d += __shfl_xor(d, off, 64);
    if (sl == 0) {
      // positive doubles order as uint64; low 12 mantissa bits -> index (ties: lower k)
      unsigned long long key =
          ((unsigned long long)__double_as_longlong(d) & ~0xFFFull) | (unsigned long long)k;
      atomicMin(&best[rl], key);
    }
  }
  __syncthreads();
  if (t < TILE_M) out[rowBlock + t] = (int)(best[t] & 0xFFFull);
}

extern "C" void kernel_launch(void* const* d_in, const int* in_sizes, int n_in,
                              void* d_out, int out_size, void* d_ws, size_t ws_size,
                              hipStream_t stream) {
  const float* x = (const float*)d_in[0];
  const float* cent = (const float*)d_in[1];
  int* out = (int*)d_out;
  const size_t nXq = (size_t)N_ROWS * DIM;          // 32 MiB fp8
  const size_t nCq = (size_t)K_CENT * DIM;          // 2 MiB fp8
  const size_t nCsq = (size_t)K_CENT * sizeof(float);
  const int grid = N_ROWS / TILE_M;                 // 512 blocks

  if (ws_size >= nXq + nCq + nCsq) {
    unsigned char* xq = (unsigned char*)d_ws;
    unsigned char* cq = xq + nXq;
    float* csqg = (float*)(cq + nCq);
    const size_t total8 = ((size_t)N_ROWS + K_CENT) * DIM / 8;
    prep_convert<<<(unsigned)((total8 + 255) / 256), 256, 0, stream>>>(x, cent, xq, cq, csqg);
    kmeans_argmin<2><<<grid, THREADS, 0, stream>>>(x, cent, xq, cq, csqg, out);
  } else {
    kmeans_argmin<0><<<grid, THREADS, 0, stream>>>(x, cent, nullptr, nullptr, nullptr, out);
  }
}

// Round 7
// 626.801 us; speedup vs baseline: 2.7042x; 2.7042x over previous
//
#include <hip/hip_runtime.h>

#define N_ROWS 65536
#define DIM    512
#define K_CENT 4096
#define TILE_M 128
#define TILE_N 128
#define BK     64
#define KSTEPS (DIM / BK)        // 8
#define NKT    (K_CENT / TILE_N) // 32
#define THREADS 512
#define MARGIN 22.0f
#define CAND_CAP 1536
#define COMPACT_TRIG 1024
#define SCALE1 0x7F7F7F7F        // e8m0 scale = 2^0 in every byte

typedef float  floatx4  __attribute__((ext_vector_type(4)));
typedef float  floatx16 __attribute__((ext_vector_type(16)));
typedef int    intx2    __attribute__((ext_vector_type(2)));
typedef int    intx4    __attribute__((ext_vector_type(4)));
typedef int    intx8    __attribute__((ext_vector_type(8)));

// order-preserving float<->uint map
__device__ __forceinline__ unsigned mapF(float f) {
  unsigned u = __float_as_uint(f);
  return (u & 0x80000000u) ? ~u : (u | 0x80000000u);
}
__device__ __forceinline__ float unmapF(unsigned m) {
  unsigned u = (m & 0x80000000u) ? (m ^ 0x80000000u) : ~m;
  return __uint_as_float(u);
}

__device__ __forceinline__ void gload_lds16(const void* g, void* l) {
  __builtin_amdgcn_global_load_lds(
      (const __attribute__((address_space(1))) void*)g,
      (__attribute__((address_space(3))) void*)l, 16, 0, 0);
}

// pack 4 floats -> 4 OCP e4m3 bytes
__device__ __forceinline__ int pk4(float a, float b, float c, float d) {
  int r = __builtin_amdgcn_cvt_pk_fp8_f32(a, b, 0, false);
  r = __builtin_amdgcn_cvt_pk_fp8_f32(c, d, r, true);
  return r;
}

// fp32 -> fp8 for x and center; EXACT fp32 csq fused into the center branch
__global__ void prep_convert(const float* __restrict__ x, const float* __restrict__ c,
                             unsigned char* __restrict__ xq, unsigned char* __restrict__ cq,
                             float* __restrict__ csqg) {
  const size_t nx = (size_t)N_ROWS * DIM;
  size_t i = ((size_t)blockIdx.x * blockDim.x + threadIdx.x) * 8;
  if (i < nx) {
    floatx4 a = *(const floatx4*)(x + i);
    floatx4 b = *(const floatx4*)(x + i + 4);
    intx2 q = { pk4(a[0], a[1], a[2], a[3]), pk4(b[0], b[1], b[2], b[3]) };
    *(intx2*)(xq + i) = q;
  } else if (i < nx + (size_t)K_CENT * DIM) {
    size_t off = i - nx;
    floatx4 a = *(const floatx4*)(c + off);
    floatx4 b = *(const floatx4*)(c + off + 4);
    intx2 q = { pk4(a[0], a[1], a[2], a[3]), pk4(b[0], b[1], b[2], b[3]) };
    *(intx2*)(cq + off) = q;
    float s = a[0]*a[0]+a[1]*a[1]+a[2]*a[2]+a[3]*a[3]
            + b[0]*b[0]+b[1]*b[1]+b[2]*b[2]+b[3]*b[3];
#pragma unroll
    for (int o = 1; o < 64; o <<= 1) s += __shfl_xor(s, o, 64);
    if ((threadIdx.x & 63) == 0) csqg[off >> 9] = s;
  }
}

// MODE 0: no ws (fp32 loads, in-kernel fp8 cvt + ds_write, LDS csq)
// MODE 2: fp8 + exact-fp32 csq pre-computed in ws
//
// 512 threads = 8 waves (4 row-waves x 2 col-waves), block tile 128x128,
// wave tile 32x64 = 1x2 of mfma_scale_f32_32x32x64_f8f6f4 (unit scales),
// BK=64 -> KSTEPS=8, grid 512 (2 blocks/CU, 16 waves).
// REGISTER BUDGET IS THE BINDING CONSTRAINT (R4 & R6 both died to acc spill:
// WRITE_SIZE GBs + MfmaUtil ~3%): acc 2x16=32 + frags 24 + misc ~40 < 128
// with __launch_bounds__(512,4). Do not grow the wave acc tile past 32 f32
// with the scaled-MFMA path.
// Single pass: tighten per-row running min (shfl-reduced over 32 cols),
// barrier, collect vs runmin+MARGIN (prefix superset), fp64-exact refine.
// LDS tile layout: 16B slot s = rg*128 + r32*4 + (c ^ ((r32>>1)&3));
// glds-compatible (lane-contiguous slots) and low-conflict b128 reads.
template <int MODE>
__global__ __launch_bounds__(THREADS, 4)
void kmeans_argmin(const float* __restrict__ x, const float* __restrict__ cent,
                   const unsigned char* __restrict__ xq, const unsigned char* __restrict__ cq,
                   const float* __restrict__ csqg, int* __restrict__ out) {
  __shared__ unsigned char ldsA[TILE_M * BK];   // 8 KB  (512 slots)
  __shared__ unsigned char ldsB[TILE_N * BK];   // 8 KB  (512 slots)
  __shared__ float csq4[TILE_N][4];             // 2 KB (MODE 0 only)
  __shared__ unsigned sminU[TILE_M];
  __shared__ unsigned long long best[TILE_M];
  __shared__ unsigned candKey[CAND_CAP];        // 6 KB
  __shared__ float candS[CAND_CAP];             // 6 KB
  __shared__ int candCount;

  const int t = threadIdx.x;
  const int lane = t & 63;
  const int wave = t >> 6;   // 0..7
  const int wm = wave >> 1;  // 0..3 row-waves (32 rows each)
  const int wn = wave & 1;   // 0..1 col-waves (64 cols each)
  const int l31 = lane & 31;
  const int half = lane >> 5;           // 0..1
  const int rowBlock = blockIdx.x * TILE_M;

  if (t < TILE_M) { sminU[t] = 0xFFFFFFFFu; best[t] = ~0ull; }
  if (t == 0) candCount = 0;

  // staging slot decode (A and B use the same 512-slot mapping):
  // slot s -> row = (s>>7)*32 + ((s>>2)&31),
  // chunk c = (s&3) ^ (((s>>2)&31)>>1 & 3), byte off c*16 within the row's 64B
  const int rS = (t >> 2) & 31;
  const int rowS = (t >> 7) * 32 + rS;
  const int offS = (((t & 3) ^ ((rS >> 1) & 3)) << 4);

  // fragment read slots (per lane): row r=l31 within group, chunks qk, qk^1
  const int qk = half * 2;
  const int fragSlotBase = 4 * l31 + (qk ^ ((l31 >> 1) & 3)); // + group*128; pair = ^1

  for (int kt = 0; kt < NKT; ++kt) {
    const int ktBase = kt * TILE_N;
    if (MODE == 0) ((float*)csq4)[t] = 0.f;
    floatx16 acc[2];
#pragma unroll
    for (int fn = 0; fn < 2; ++fn)
#pragma unroll
      for (int e = 0; e < 16; ++e) acc[fn][e] = 0.f;

    for (int ks = 0; ks < KSTEPS; ++ks) {
      const int kd = ks * BK;
      if (MODE == 2) {
        gload_lds16(xq + (size_t)(rowBlock + rowS) * DIM + kd + offS,
                    ldsA + (size_t)wave * 1024);
        gload_lds16(cq + (size_t)(ktBase + rowS) * DIM + kd + offS,
                    ldsB + (size_t)wave * 1024);
      } else {
        {
          const float* gA = x + (size_t)(rowBlock + rowS) * DIM + kd + offS;
          floatx4 f0 = *(const floatx4*)gA, f1 = *(const floatx4*)(gA + 4);
          floatx4 f2 = *(const floatx4*)(gA + 8), f3 = *(const floatx4*)(gA + 12);
          intx4 q = { pk4(f0[0],f0[1],f0[2],f0[3]), pk4(f1[0],f1[1],f1[2],f1[3]),
                      pk4(f2[0],f2[1],f2[2],f2[3]), pk4(f3[0],f3[1],f3[2],f3[3]) };
          *(intx4*)(ldsA + (size_t)t * 16) = q;
        }
        {
          const float* gB = cent + (size_t)(ktBase + rowS) * DIM + kd + offS;
          floatx4 f0 = *(const floatx4*)gB, f1 = *(const floatx4*)(gB + 4);
          floatx4 f2 = *(const floatx4*)(gB + 8), f3 = *(const floatx4*)(gB + 12);
          intx4 q = { pk4(f0[0],f0[1],f0[2],f0[3]), pk4(f1[0],f1[1],f1[2],f1[3]),
                      pk4(f2[0],f2[1],f2[2],f2[3]), pk4(f3[0],f3[1],f3[2],f3[3]) };
          *(intx4*)(ldsB + (size_t)t * 16) = q;
          float s = 0.f;
#pragma unroll
          for (int e = 0; e < 4; ++e)
            s += f0[e]*f0[e] + f1[e]*f1[e] + f2[e]*f2[e] + f3[e]*f3[e];
          csq4[rowS][t & 3] += s;
        }
      }
      __syncthreads();

      intx8 aF, bF[2];
      {
        int s0 = wm * 128 + fragSlotBase;
        intx4 lo = *(const intx4*)(ldsA + s0 * 16);
        intx4 hi = *(const intx4*)(ldsA + (s0 ^ 1) * 16);
        aF = (intx8){lo[0], lo[1], lo[2], lo[3], hi[0], hi[1], hi[2], hi[3]};
      }
#pragma unroll
      for (int fn = 0; fn < 2; ++fn) {
        int s0 = (wn * 2 + fn) * 128 + fragSlotBase;
        intx4 lo = *(const intx4*)(ldsB + s0 * 16);
        intx4 hi = *(const intx4*)(ldsB + (s0 ^ 1) * 16);
        bF[fn] = (intx8){lo[0], lo[1], lo[2], lo[3], hi[0], hi[1], hi[2], hi[3]};
      }
#pragma unroll
      for (int fn = 0; fn < 2; ++fn)
        acc[fn] = __builtin_amdgcn_mfma_scale_f32_32x32x64_f8f6f4(
            aF, bF[fn], acc[fn], 0, 0, 0, SCALE1, 0, SCALE1);
      __syncthreads();
    }

    // ---- epilogue: s = ||c||^2_exact - 2*cross  (||x||^2 constant per row)
    // C/D 32x32 layout: col = lane&31, row = (reg&3)+8*(reg>>2)+4*(lane>>5)
    float cs[2];
#pragma unroll
    for (int fn = 0; fn < 2; ++fn) {
      int cl = wn * 64 + fn * 32 + l31;
      cs[fn] = (MODE == 2) ? csqg[ktBase + cl]
                           : (csq4[cl][0] + csq4[cl][1] + csq4[cl][2] + csq4[cl][3]);
    }

    // tighten running min first: min over fn + shfl-reduce over the 32 cols
#pragma unroll
    for (int r = 0; r < 16; ++r) {
      float v = fminf(cs[0] - 2.f * acc[0][r], cs[1] - 2.f * acc[1][r]);
      v = fminf(v, __shfl_xor(v, 1, 64));
      v = fminf(v, __shfl_xor(v, 2, 64));
      v = fminf(v, __shfl_xor(v, 4, 64));
      v = fminf(v, __shfl_xor(v, 8, 64));
      v = fminf(v, __shfl_xor(v, 16, 64));
      if (l31 == 0) {
        int srow = wm * 32 + (r & 3) + 8 * (r >> 2) + 4 * half;
        atomicMin(&sminU[srow], mapF(v));
      }
    }
    __syncthreads();

    // collect against the tightened (prefix, hence superset) threshold
#pragma unroll
    for (int r = 0; r < 16; ++r) {
      int srow = wm * 32 + (r & 3) + 8 * (r >> 2) + 4 * half;
      float thr = unmapF(sminU[srow]) + MARGIN;
#pragma unroll
      for (int fn = 0; fn < 2; ++fn) {
        float s = cs[fn] - 2.f * acc[fn][r];
        if (s <= thr) {
          int k = ktBase + wn * 64 + fn * 32 + l31;
          int idx = atomicAdd(&candCount, 1);
          if (idx < CAND_CAP) {
            candKey[idx] = ((unsigned)k << 7) | (unsigned)srow;
            candS[idx] = s;
          }
        }
      }
    }
    __syncthreads();

    // compaction backstop (rarely triggers)
    if (candCount > COMPACT_TRIG) {
      int cc = candCount; if (cc > CAND_CAP) cc = CAND_CAP;
      unsigned myK[4]; float myS[4]; int myN = 0;
      for (int i = t; i < cc; i += THREADS) {
        int rl = candKey[i] & 127;
        if (candS[i] <= unmapF(sminU[rl]) + MARGIN && myN < 4) {
          myK[myN] = candKey[i]; myS[myN] = candS[i]; ++myN;
        }
      }
      __syncthreads();
      if (t == 0) candCount = 0;
      __syncthreads();
      int base = atomicAdd(&candCount, myN);
      for (int j = 0; j < myN; ++j) { candKey[base + j] = myK[j]; candS[base + j] = myS[j]; }
      __syncthreads();
    }
  }

  // ---- fp64-exact refinement of surviving candidates (original fp32 inputs)
  int cnt = candCount; if (cnt > CAND_CAP) cnt = CAND_CAP;
  const int g = t >> 4;   // 32 groups of 16 lanes
  const int sl = t & 15;
  for (int ci = g; ci < cnt; ci += 32) {
    unsigned cd = candKey[ci];
    int rl = cd & 127;
    if (candS[ci] > unmapF(sminU[rl]) + MARGIN) continue;  // group-uniform branch
    int k = cd >> 7;
    const float* xr = x + (size_t)(rowBlock + rl) * DIM;
    const float* cr = cent + (size_t)k * DIM;
    double d = 0.0;
#pragma unroll
    for (int j = 0; j < DIM / 64; ++j) {
      floatx4 xv = *(const floatx4*)(xr + j * 64 + sl * 4);
      floatx4 cv = *(const floatx4*)(cr + j * 64 + sl * 4);
#pragma unroll
      for (int e = 0; e < 4; ++e) {
        double df = (double)xv[e] - (double)cv[e];
        d += df * df;
      }
    }
#pragma unroll
    for (int off = 1; off < 16; off <<= 1) d += __shfl_xor(d, off, 64);
    if (sl == 0) {
      // positive doubles order as uint64; low 12 mantissa bits -> index (ties: lower k)
      unsigned long long key =
          ((unsigned long long)__double_as_longlong(d) & ~0xFFFull) | (unsigned long long)k;
      atomicMin(&best[rl], key);
    }
  }
  __syncthreads();
  if (t < TILE_M) out[rowBlock + t] = (int)(best[t] & 0xFFFull);
}

extern "C" void kernel_launch(void* const* d_in, const int* in_sizes, int n_in,
                              void* d_out, int out_size, void* d_ws, size_t ws_size,
                              hipStream_t stream) {
  const float* x = (const float*)d_in[0];
  const float* cent = (const float*)d_in[1];
  int* out = (int*)d_out;
  const size_t nXq = (size_t)N_ROWS * DIM;          // 32 MiB fp8
  const size_t nCq = (size_t)K_CENT * DIM;          // 2 MiB fp8
  const size_t nCsq = (size_t)K_CENT * sizeof(float);
  const int grid = N_ROWS / TILE_M;                 // 512 blocks

  if (ws_size >= nXq + nCq + nCsq) {
    unsigned char* xq = (unsigned char*)d_ws;
    unsigned char* cq = xq + nXq;
    float* csqg = (float*)(cq + nCq);
    const size_t total8 = ((size_t)N_ROWS + K_CENT) * DIM / 8;
    prep_convert<<<(unsigned)((total8 + 255) / 256), 256, 0, stream>>>(x, cent, xq, cq, csqg);
    kmeans_argmin<2><<<grid, THREADS, 0, stream>>>(x, cent, xq, cq, csqg, out);
  } else {
    kmeans_argmin<0><<<grid, THREADS, 0, stream>>>(x, cent, nullptr, nullptr, nullptr, out);
  }
}